// Round 1
// baseline (56.225 us; speedup 1.0000x reference)
//
#include <hip/hip_runtime.h>

// Problem constants (from reference): B=8, T=4096, NC=2048, D=1024
#define BATCH 8
#define TLEN  4096
#define NCHUNK 2048
#define DMODEL 1024

// ---------------------------------------------------------------------------
// Kernel 1: per-batch exclusive cumsum of boundary flags, clamped to NC-1.
// One block per batch, 256 threads, 16 elements/thread (T = 4096).
// ---------------------------------------------------------------------------
__global__ void dechunk_scan_kernel(const int* __restrict__ bflag,
                                    int* __restrict__ idx) {
    const int batch = blockIdx.x;
    const int tid = threadIdx.x;                  // 0..255
    const int* bb = bflag + (size_t)batch * TLEN;
    int* ii = idx + (size_t)batch * TLEN;

    const int base = tid * 16;
    int vals[16];
    int s = 0;
    const int4* bv = (const int4*)(bb + base);
#pragma unroll
    for (int k = 0; k < 4; ++k) {
        int4 v = bv[k];
        vals[4 * k + 0] = v.x; vals[4 * k + 1] = v.y;
        vals[4 * k + 2] = v.z; vals[4 * k + 3] = v.w;
        s += v.x + v.y + v.z + v.w;
    }

    // Exclusive scan of per-thread sums across 256 threads (Hillis-Steele).
    __shared__ int sm[256];
    sm[tid] = s;
    __syncthreads();
#pragma unroll
    for (int off = 1; off < 256; off <<= 1) {
        int v = (tid >= off) ? sm[tid - off] : 0;
        __syncthreads();
        sm[tid] += v;
        __syncthreads();
    }
    int run = sm[tid] - s;  // exclusive prefix for this thread's first element

    int outv[16];
#pragma unroll
    for (int k = 0; k < 16; ++k) {
        outv[k] = min(run, NCHUNK - 1);  // clamp; values are >= 0 already
        run += vals[k];
    }
    int4* iv = (int4*)(ii + base);
#pragma unroll
    for (int k = 0; k < 4; ++k) {
        iv[k] = make_int4(outv[4 * k + 0], outv[4 * k + 1],
                          outv[4 * k + 2], outv[4 * k + 3]);
    }
}

// ---------------------------------------------------------------------------
// Kernel 2: one block per output row [b,t]; 256 threads x float4 = 1024 floats.
// out[b,t,:] = p[b,t]*z[b,idx[t],:] + (1-p[b,t])*z[b,idx[t-1],:]
// t==0 -> copy z[b,idx[0],:]; idx[t]==idx[t-1] -> copy (blend is identity).
// All branches are block-uniform (depend only on t / idx), so no divergence.
// ---------------------------------------------------------------------------
__global__ void dechunk_smooth_kernel(const float* __restrict__ z,
                                      const float* __restrict__ p,
                                      const int* __restrict__ idx,
                                      float* __restrict__ out) {
    const int bt = blockIdx.x;              // batch*TLEN + t
    const int t = bt & (TLEN - 1);
    const int batch = bt / TLEN;
    const int tid = threadIdx.x;            // 0..255

    const int cur = idx[bt];
    const float4* __restrict__ zc =
        (const float4*)(z + ((size_t)batch * NCHUNK + cur) * DMODEL);
    float4* outr = (float4*)(out + (size_t)bt * DMODEL);

    if (t == 0) {
        outr[tid] = zc[tid];
        return;
    }
    const int prev = idx[bt - 1];
    if (prev == cur) {
        // p*x + (1-p)*x == x up to 1-2 ulp; copy is exact and skips a row read.
        outr[tid] = zc[tid];
        return;
    }
    const float pv = p[bt];
    const float q = 1.0f - pv;
    const float4* __restrict__ zp =
        (const float4*)(z + ((size_t)batch * NCHUNK + prev) * DMODEL);
    float4 a = zc[tid];
    float4 r = zp[tid];
    float4 o;
    o.x = pv * a.x + q * r.x;
    o.y = pv * a.y + q * r.y;
    o.z = pv * a.z + q * r.z;
    o.w = pv * a.w + q * r.w;
    outr[tid] = o;
}

extern "C" void kernel_launch(void* const* d_in, const int* in_sizes, int n_in,
                              void* d_out, int out_size, void* d_ws, size_t ws_size,
                              hipStream_t stream) {
    const float* z = (const float*)d_in[0];       // [B, NC, D] fp32
    const float* p = (const float*)d_in[1];       // [B, T] fp32
    const int* bflag = (const int*)d_in[2];       // [B, T] int32
    // d_in[3] = original_len (scalar) — statically T, unused.
    float* out = (float*)d_out;                   // [B, T, D] fp32
    int* idx = (int*)d_ws;                        // B*T ints = 128 KiB scratch

    dechunk_scan_kernel<<<BATCH, 256, 0, stream>>>(bflag, idx);
    dechunk_smooth_kernel<<<BATCH * TLEN, 256, 0, stream>>>(z, p, idx, out);
}

// Round 2
// 42.202 us; speedup vs baseline: 1.3323x; 1.3323x over previous
//
#include <hip/hip_runtime.h>

// Problem constants (from reference): B=8, T=4096, NC=2048, D=1024
#define BATCH 8
#define TLEN  4096
#define NCHUNK 2048
#define DMODEL 1024
#define ROWS_PER_BLOCK 16   // t rows handled per block (register-carry chain)

// ---------------------------------------------------------------------------
// Kernel 1: per-batch exclusive cumsum of boundary flags, clamped to NC-1.
// One block per batch, 256 threads, 16 elements/thread (T = 4096).
// ---------------------------------------------------------------------------
__global__ void dechunk_scan_kernel(const int* __restrict__ bflag,
                                    int* __restrict__ idx) {
    const int batch = blockIdx.x;
    const int tid = threadIdx.x;                  // 0..255
    const int* bb = bflag + (size_t)batch * TLEN;
    int* ii = idx + (size_t)batch * TLEN;

    const int base = tid * 16;
    int vals[16];
    int s = 0;
    const int4* bv = (const int4*)(bb + base);
#pragma unroll
    for (int k = 0; k < 4; ++k) {
        int4 v = bv[k];
        vals[4 * k + 0] = v.x; vals[4 * k + 1] = v.y;
        vals[4 * k + 2] = v.z; vals[4 * k + 3] = v.w;
        s += v.x + v.y + v.z + v.w;
    }

    // Exclusive scan of per-thread sums across 256 threads (Hillis-Steele).
    __shared__ int sm[256];
    sm[tid] = s;
    __syncthreads();
#pragma unroll
    for (int off = 1; off < 256; off <<= 1) {
        int v = (tid >= off) ? sm[tid - off] : 0;
        __syncthreads();
        sm[tid] += v;
        __syncthreads();
    }
    int run = sm[tid] - s;  // exclusive prefix for this thread's first element

    int outv[16];
#pragma unroll
    for (int k = 0; k < 16; ++k) {
        outv[k] = min(run, NCHUNK - 1);  // clamp; values are >= 0 already
        run += vals[k];
    }
    int4* iv = (int4*)(ii + base);
#pragma unroll
    for (int k = 0; k < 4; ++k) {
        iv[k] = make_int4(outv[4 * k + 0], outv[4 * k + 1],
                          outv[4 * k + 2], outv[4 * k + 3]);
    }
}

// ---------------------------------------------------------------------------
// Kernel 2: one block per 16 consecutive t rows of one batch.
// 256 threads x float4 = 1024 floats = one full D row per iteration.
// Key identity: rolled[t] == upsampled[t-1], which is exactly the row value
// this block computed on the previous iteration -> carry it in a register.
// Each distinct z row is loaded at most once per block; when idx doesn't
// advance (about half of all rows) no load at all. All branches are
// block-uniform (depend only on idx values staged in LDS).
// ---------------------------------------------------------------------------
__global__ void dechunk_smooth_kernel(const float* __restrict__ z,
                                      const float* __restrict__ p,
                                      const int* __restrict__ idx,
                                      float* __restrict__ out) {
    const int chunks_per_batch = TLEN / ROWS_PER_BLOCK;
    const int chunk = blockIdx.x;
    const int batch = chunk / chunks_per_batch;
    const int t0 = (chunk - batch * chunks_per_batch) * ROWS_PER_BLOCK;
    const int tid = threadIdx.x;                  // 0..255
    const int bt0 = batch * TLEN + t0;

    __shared__ int lidx[ROWS_PER_BLOCK + 1];      // idx[t0-1 .. t0+15]
    __shared__ float lp[ROWS_PER_BLOCK];          // p[t0 .. t0+15]
    if (tid < ROWS_PER_BLOCK + 1) {
        int g = bt0 - 1 + tid;
        lidx[tid] = idx[max(g, 0)];               // g=-1 only when batch==0,t0==0 (unused)
    } else if (tid >= 64 && tid < 64 + ROWS_PER_BLOCK) {
        lp[tid - 64] = p[bt0 + (tid - 64)];
    }
    __syncthreads();

    const float* zb = z + (size_t)batch * NCHUNK * DMODEL;
    float4* outr = (float4*)(out + (size_t)bt0 * DMODEL);

    int last_i;          // idx of the row currently held in `val`
    float4 val;          // z[last_i] slice for this thread
    int j0 = 0;

    if (t0 == 0) {
        // Row 0 is a pure copy of upsampled[0].
        last_i = lidx[1];
        val = ((const float4*)(zb + (size_t)last_i * DMODEL))[tid];
        outr[tid] = val;
        j0 = 1;
    } else {
        last_i = lidx[0];                          // idx[t0-1]
        val = ((const float4*)(zb + (size_t)last_i * DMODEL))[tid];
    }

    for (int j = j0; j < ROWS_PER_BLOCK; ++j) {
        const int ci = lidx[j + 1];                // idx[t0+j]
        float4 o;
        if (ci == last_i) {
            // p*x + (1-p)*x == x (exact copy path, skips the load entirely)
            o = val;
        } else {
            float4 nv = ((const float4*)(zb + (size_t)ci * DMODEL))[tid];
            const float pv = lp[j];
            const float q = 1.0f - pv;
            o.x = pv * nv.x + q * val.x;
            o.y = pv * nv.y + q * val.y;
            o.z = pv * nv.z + q * val.z;
            o.w = pv * nv.w + q * val.w;
            val = nv;
            last_i = ci;
        }
        outr[j * (DMODEL / 4) + tid] = o;
    }
}

extern "C" void kernel_launch(void* const* d_in, const int* in_sizes, int n_in,
                              void* d_out, int out_size, void* d_ws, size_t ws_size,
                              hipStream_t stream) {
    const float* z = (const float*)d_in[0];       // [B, NC, D] fp32
    const float* p = (const float*)d_in[1];       // [B, T] fp32
    const int* bflag = (const int*)d_in[2];       // [B, T] int32
    // d_in[3] = original_len (scalar) — statically T, unused.
    float* out = (float*)d_out;                   // [B, T, D] fp32
    int* idx = (int*)d_ws;                        // B*T ints = 128 KiB scratch

    dechunk_scan_kernel<<<BATCH, 256, 0, stream>>>(bflag, idx);
    dechunk_smooth_kernel<<<BATCH * (TLEN / ROWS_PER_BLOCK), 256, 0, stream>>>(
        z, p, idx, out);
}

// Round 3
// 41.441 us; speedup vs baseline: 1.3568x; 1.0184x over previous
//
#include <hip/hip_runtime.h>

// Problem constants (from reference): B=8, T=4096, NC=2048, D=1024
#define BATCH 8
#define TLEN  4096
#define NCHUNK 2048
#define DMODEL 1024
#define ROWS_PER_BLOCK 16   // t rows handled per block

// ---------------------------------------------------------------------------
// Kernel 1: per-batch exclusive cumsum of boundary flags, clamped to NC-1.
// One block per batch, 256 threads, 16 elements/thread (T = 4096).
// Wave-level shfl scan (6 steps) + one LDS stage across the 4 waves.
// ---------------------------------------------------------------------------
__global__ void dechunk_scan_kernel(const int* __restrict__ bflag,
                                    int* __restrict__ idx) {
    const int batch = blockIdx.x;
    const int tid = threadIdx.x;                  // 0..255
    const int lane = tid & 63;
    const int wid = tid >> 6;                     // 0..3
    const int* bb = bflag + (size_t)batch * TLEN;
    int* ii = idx + (size_t)batch * TLEN;

    const int base = tid * 16;
    int vals[16];
    int s = 0;
    const int4* bv = (const int4*)(bb + base);
#pragma unroll
    for (int k = 0; k < 4; ++k) {
        int4 v = bv[k];
        vals[4 * k + 0] = v.x; vals[4 * k + 1] = v.y;
        vals[4 * k + 2] = v.z; vals[4 * k + 3] = v.w;
        s += v.x + v.y + v.z + v.w;
    }

    // Inclusive scan of per-thread sums within each 64-lane wave.
    int incl = s;
#pragma unroll
    for (int off = 1; off < 64; off <<= 1) {
        int n = __shfl_up(incl, off, 64);
        if (lane >= off) incl += n;
    }

    __shared__ int wsum[4];
    if (lane == 63) wsum[wid] = incl;
    __syncthreads();
    int woff = 0;
#pragma unroll
    for (int w = 0; w < 4; ++w)
        woff += (w < wid) ? wsum[w] : 0;

    int run = woff + incl - s;   // exclusive prefix for this thread's elem 0

    int outv[16];
#pragma unroll
    for (int k = 0; k < 16; ++k) {
        outv[k] = min(run, NCHUNK - 1);  // clamp; values are >= 0 already
        run += vals[k];
    }
    int4* iv = (int4*)(ii + base);
#pragma unroll
    for (int k = 0; k < 4; ++k) {
        iv[k] = make_int4(outv[4 * k + 0], outv[4 * k + 1],
                          outv[4 * k + 2], outv[4 * k + 3]);
    }
}

// ---------------------------------------------------------------------------
// Kernel 2: one block per 16 consecutive t rows of one batch.
// 256 threads x float4 = 1024 floats = one full D row per store.
// All 17 candidate row loads are unconditional and depend only on LDS-staged
// idx values -> compiler can issue them back-to-back (high MLP) instead of
// one-at-a-time behind a serial branch chain. Duplicate rows (idx didn't
// advance) are same-address re-loads from the same wave -> L1 hits, so HBM
// read traffic stays ~= distinct rows only. Blend p*x+(1-p)*x when rows are
// equal differs from an exact copy by <=1 ulp (far below the harness
// threshold, measured absmax 0.0156 with exact copies).
// ---------------------------------------------------------------------------
__global__ void dechunk_smooth_kernel(const float* __restrict__ z,
                                      const float* __restrict__ p,
                                      const int* __restrict__ idx,
                                      float* __restrict__ out) {
    const int chunks_per_batch = TLEN / ROWS_PER_BLOCK;   // 256
    const int chunk = blockIdx.x;
    const int batch = chunk / chunks_per_batch;
    const int t0 = (chunk - batch * chunks_per_batch) * ROWS_PER_BLOCK;
    const int tid = threadIdx.x;                  // 0..255
    const int bt0 = batch * TLEN + t0;

    __shared__ int lidx[ROWS_PER_BLOCK + 1];      // idx[t0-1 .. t0+15]
    __shared__ float lp[ROWS_PER_BLOCK];          // p[t0 .. t0+15]
    if (tid < ROWS_PER_BLOCK + 1) {
        int g = bt0 - 1 + tid;
        lidx[tid] = idx[max(g, 0)];  // t0==0: lidx[0] is unused garbage (valid row)
    } else if (tid >= 32 && tid < 32 + ROWS_PER_BLOCK) {
        lp[tid - 32] = p[bt0 + (tid - 32)];
    }
    __syncthreads();

    const float* zb = z + (size_t)batch * NCHUNK * DMODEL;
    float4* outr = (float4*)(out + (size_t)bt0 * DMODEL);

    // Unconditional hoisted loads: addresses known after the barrier.
    float4 v[ROWS_PER_BLOCK + 1];
#pragma unroll
    for (int j = 0; j <= ROWS_PER_BLOCK; ++j) {
        v[j] = ((const float4*)(zb + (size_t)lidx[j] * DMODEL))[tid];
    }

#pragma unroll
    for (int j = 0; j < ROWS_PER_BLOCK; ++j) {
        float4 a = v[j + 1];   // upsampled[t0+j]
        float4 o;
        if (j == 0 && t0 == 0) {
            o = a;             // row 0 is a pure copy (block-uniform branch)
        } else {
            float4 r = v[j];   // rolled = upsampled[t0+j-1]
            const float pv = lp[j];
            const float q = 1.0f - pv;
            o.x = pv * a.x + q * r.x;
            o.y = pv * a.y + q * r.y;
            o.z = pv * a.z + q * r.z;
            o.w = pv * a.w + q * r.w;
        }
        outr[j * (DMODEL / 4) + tid] = o;
    }
}

extern "C" void kernel_launch(void* const* d_in, const int* in_sizes, int n_in,
                              void* d_out, int out_size, void* d_ws, size_t ws_size,
                              hipStream_t stream) {
    const float* z = (const float*)d_in[0];       // [B, NC, D] fp32
    const float* p = (const float*)d_in[1];       // [B, T] fp32
    const int* bflag = (const int*)d_in[2];       // [B, T] int32
    // d_in[3] = original_len (scalar) — statically T, unused.
    float* out = (float*)d_out;                   // [B, T, D] fp32
    int* idx = (int*)d_ws;                        // B*T ints = 128 KiB scratch

    dechunk_scan_kernel<<<BATCH, 256, 0, stream>>>(bflag, idx);
    dechunk_smooth_kernel<<<BATCH * (TLEN / ROWS_PER_BLOCK), 256, 0, stream>>>(
        z, p, idx, out);
}

// Round 4
// 37.468 us; speedup vs baseline: 1.5006x; 1.1060x over previous
//
#include <hip/hip_runtime.h>

// Problem constants (from reference): B=8, T=4096, NC=2048, D=1024
#define BATCH 8
#define TLEN  4096
#define NCHUNK 2048
#define DMODEL 1024
#define ROWS_PER_BLOCK 16   // t rows handled per block

// ---------------------------------------------------------------------------
// Single fused kernel: one block per 16 consecutive t rows of one batch.
//
// idx[t] = min(exclusive_cumsum(b)[t], NC-1). Instead of a separate scan
// kernel (8 workgroups, pure latency, serializes the stream), each block
// recomputes its own idx window directly from b:
//   base    = sum(b[0 .. t0-2])            (masked block reduce, b is
//                                           L2-resident: 16 KB/batch row)
//   e_j     = base + prefix_j(window)      (17-element LDS prefix)
//   lidx[j] = min(e_j, NC-1),  j=0..16  == idx[t0-1 .. t0+15]
//
// Blend: out[t] = p[t]*z[idx[t]] + (1-p[t])*z[idx[t-1]]; out[0] = z[idx[0]].
// All 17 candidate row loads are unconditional (addresses known after one
// barrier) -> high memory-level parallelism; duplicate rows are same-address
// wave loads -> L1 hits, HBM read ~= distinct rows only.
// ---------------------------------------------------------------------------
__global__ void dechunk_fused_kernel(const float* __restrict__ z,
                                     const float* __restrict__ p,
                                     const int* __restrict__ bflag,
                                     float* __restrict__ out) {
    const int chunks_per_batch = TLEN / ROWS_PER_BLOCK;   // 256
    const int chunk = blockIdx.x;
    const int batch = chunk / chunks_per_batch;
    const int t0 = (chunk - batch * chunks_per_batch) * ROWS_PER_BLOCK;
    const int tid = threadIdx.x;                  // 0..255
    const int lane = tid & 63;
    const int wid = tid >> 6;                     // 0..3
    const int bt0 = batch * TLEN + t0;
    const int* bb = bflag + (size_t)batch * TLEN;

    __shared__ int wsum[4];                       // per-wave partial sums
    __shared__ int wlds[ROWS_PER_BLOCK + 1];      // b window [t0-1 .. t0+15]
    __shared__ int lidx[ROWS_PER_BLOCK + 1];      // idx[t0-1 .. t0+15]
    __shared__ float lp[ROWS_PER_BLOCK];          // p[t0 .. t0+15]

    // --- base = sum(b[0 .. t0-2]), i.e. first (t0-1) elements, masked ---
    const int limit = t0 - 1;                     // block-uniform
    int s = 0;
    const int eu = tid * 16;
    if (eu < limit) {
        const int4* bv4 = (const int4*)(bb + eu);
#pragma unroll
        for (int k = 0; k < 4; ++k) {
            int4 v = bv4[k];
            const int u = eu + 4 * k;
            s += (u + 0 < limit) ? v.x : 0;
            s += (u + 1 < limit) ? v.y : 0;
            s += (u + 2 < limit) ? v.z : 0;
            s += (u + 3 < limit) ? v.w : 0;
        }
    }
#pragma unroll
    for (int off = 32; off > 0; off >>= 1)
        s += __shfl_xor(s, off, 64);
    if (lane == 0) wsum[wid] = s;

    // --- stage the 17-element b window and the 16 p values ---
    if (tid < ROWS_PER_BLOCK + 1) {
        // w[0] corresponds to b[t0-1]; at t0==0 force 0 (empty-sum semantics)
        wlds[tid] = (t0 == 0 && tid == 0) ? 0 : bb[t0 - 1 + tid];
    } else if (tid >= 32 && tid < 32 + ROWS_PER_BLOCK) {
        lp[tid - 32] = p[bt0 + (tid - 32)];
    }
    __syncthreads();

    // --- 17-element prefix -> lidx (threads 0..16, same wave) ---
    if (tid < ROWS_PER_BLOCK + 1) {
        int e = wsum[0] + wsum[1] + wsum[2] + wsum[3];
        for (int u = 0; u < tid; ++u) e += wlds[u];
        lidx[tid] = min(e, NCHUNK - 1);
    }
    __syncthreads();

    // --- blend: 256 threads x float4 = one full D row per store ---
    const float* zb = z + (size_t)batch * NCHUNK * DMODEL;
    float4* outr = (float4*)(out + (size_t)bt0 * DMODEL);

    float4 v[ROWS_PER_BLOCK + 1];
#pragma unroll
    for (int j = 0; j <= ROWS_PER_BLOCK; ++j) {
        v[j] = ((const float4*)(zb + (size_t)lidx[j] * DMODEL))[tid];
    }

#pragma unroll
    for (int j = 0; j < ROWS_PER_BLOCK; ++j) {
        float4 a = v[j + 1];   // upsampled[t0+j]
        float4 o;
        if (j == 0 && t0 == 0) {
            o = a;             // row 0 is a pure copy (block-uniform branch)
        } else {
            float4 r = v[j];   // rolled = upsampled[t0+j-1]
            const float pv = lp[j];
            const float q = 1.0f - pv;
            o.x = pv * a.x + q * r.x;
            o.y = pv * a.y + q * r.y;
            o.z = pv * a.z + q * r.z;
            o.w = pv * a.w + q * r.w;
        }
        outr[j * (DMODEL / 4) + tid] = o;
    }
}

extern "C" void kernel_launch(void* const* d_in, const int* in_sizes, int n_in,
                              void* d_out, int out_size, void* d_ws, size_t ws_size,
                              hipStream_t stream) {
    const float* z = (const float*)d_in[0];       // [B, NC, D] fp32
    const float* p = (const float*)d_in[1];       // [B, T] fp32
    const int* bflag = (const int*)d_in[2];       // [B, T] int32
    // d_in[3] = original_len (scalar) — statically T, unused.
    float* out = (float*)d_out;                   // [B, T, D] fp32

    dechunk_fused_kernel<<<BATCH * (TLEN / ROWS_PER_BLOCK), 256, 0, stream>>>(
        z, p, bflag, out);
}

// Round 6
// 37.403 us; speedup vs baseline: 1.5032x; 1.0017x over previous
//
#include <hip/hip_runtime.h>

// Problem constants (from reference): B=8, T=4096, NC=2048, D=1024
#define BATCH 8
#define TLEN  4096
#define NCHUNK 2048
#define DMODEL 1024
#define ROWS_PER_BLOCK 16   // t rows handled per block

typedef float f32x4 __attribute__((ext_vector_type(4)));  // native vec for nontemporal builtin

// ---------------------------------------------------------------------------
// Single fused kernel: one block per 16 consecutive t rows of one batch.
//
// idx[t] = min(exclusive_cumsum(b)[t], NC-1). Each block recomputes its own
// idx window directly from b (b row = 16 KB/batch, L2-resident):
//   base    = sum(b[0 .. t0-2])            (masked block reduce)
//   lidx[j] = min(base + prefix_j, NC-1),  j=0..16  == idx[t0-1 .. t0+15]
//
// Blend: out[t] = p[t]*z[idx[t]] + (1-p[t])*z[idx[t-1]]; out[0] = z[idx[0]].
// All 17 candidate row loads are unconditional (addresses known after one
// barrier) -> high memory-level parallelism; duplicate rows are same-address
// wave loads -> L1 hits, HBM read ~= distinct rows only.
//
// Stores are NONTEMPORAL: out is a 134 MB write-once stream; keeping it out
// of L2/L3 preserves cache residency for z (64 MB, re-read by neighboring
// blocks on other XCDs).
// ---------------------------------------------------------------------------
__global__ void dechunk_fused_kernel(const float* __restrict__ z,
                                     const float* __restrict__ p,
                                     const int* __restrict__ bflag,
                                     float* __restrict__ out) {
    const int chunks_per_batch = TLEN / ROWS_PER_BLOCK;   // 256
    const int chunk = blockIdx.x;
    const int batch = chunk / chunks_per_batch;
    const int t0 = (chunk - batch * chunks_per_batch) * ROWS_PER_BLOCK;
    const int tid = threadIdx.x;                  // 0..255
    const int lane = tid & 63;
    const int wid = tid >> 6;                     // 0..3
    const int bt0 = batch * TLEN + t0;
    const int* bb = bflag + (size_t)batch * TLEN;

    __shared__ int wsum[4];                       // per-wave partial sums
    __shared__ int wlds[ROWS_PER_BLOCK + 1];      // b window [t0-1 .. t0+15]
    __shared__ int lidx[ROWS_PER_BLOCK + 1];      // idx[t0-1 .. t0+15]
    __shared__ float lp[ROWS_PER_BLOCK];          // p[t0 .. t0+15]

    // --- base = sum(b[0 .. t0-2]), i.e. first (t0-1) elements, masked ---
    const int limit = t0 - 1;                     // block-uniform
    int s = 0;
    const int eu = tid * 16;
    if (eu < limit) {
        const int4* bv4 = (const int4*)(bb + eu);
#pragma unroll
        for (int k = 0; k < 4; ++k) {
            int4 v = bv4[k];
            const int u = eu + 4 * k;
            s += (u + 0 < limit) ? v.x : 0;
            s += (u + 1 < limit) ? v.y : 0;
            s += (u + 2 < limit) ? v.z : 0;
            s += (u + 3 < limit) ? v.w : 0;
        }
    }
#pragma unroll
    for (int off = 32; off > 0; off >>= 1)
        s += __shfl_xor(s, off, 64);
    if (lane == 0) wsum[wid] = s;

    // --- stage the 17-element b window and the 16 p values ---
    if (tid < ROWS_PER_BLOCK + 1) {
        // wlds[0] is b[t0-1]; at t0==0 force 0 (empty-sum semantics)
        wlds[tid] = (t0 == 0 && tid == 0) ? 0 : bb[t0 - 1 + tid];
    } else if (tid >= 32 && tid < 32 + ROWS_PER_BLOCK) {
        lp[tid - 32] = p[bt0 + (tid - 32)];
    }
    __syncthreads();

    // --- 17-element prefix -> lidx (threads 0..16, same wave) ---
    if (tid < ROWS_PER_BLOCK + 1) {
        int e = wsum[0] + wsum[1] + wsum[2] + wsum[3];
        for (int u = 0; u < tid; ++u) e += wlds[u];
        lidx[tid] = min(e, NCHUNK - 1);
    }
    __syncthreads();

    // --- blend: 256 threads x float4 = one full D row per store ---
    const float* zb = z + (size_t)batch * NCHUNK * DMODEL;
    f32x4* outr = (f32x4*)(out + (size_t)bt0 * DMODEL);

    float4 v[ROWS_PER_BLOCK + 1];
#pragma unroll
    for (int j = 0; j <= ROWS_PER_BLOCK; ++j) {
        v[j] = ((const float4*)(zb + (size_t)lidx[j] * DMODEL))[tid];
    }

#pragma unroll
    for (int j = 0; j < ROWS_PER_BLOCK; ++j) {
        float4 a = v[j + 1];   // upsampled[t0+j]
        f32x4 o;
        if (j == 0 && t0 == 0) {
            o = (f32x4){a.x, a.y, a.z, a.w};  // row 0: pure copy (uniform branch)
        } else {
            float4 r = v[j];   // rolled = upsampled[t0+j-1]
            const float pv = lp[j];
            const float q = 1.0f - pv;
            o.x = pv * a.x + q * r.x;
            o.y = pv * a.y + q * r.y;
            o.z = pv * a.z + q * r.z;
            o.w = pv * a.w + q * r.w;
        }
        __builtin_nontemporal_store(o, &outr[j * (DMODEL / 4) + tid]);
    }
}

extern "C" void kernel_launch(void* const* d_in, const int* in_sizes, int n_in,
                              void* d_out, int out_size, void* d_ws, size_t ws_size,
                              hipStream_t stream) {
    const float* z = (const float*)d_in[0];       // [B, NC, D] fp32
    const float* p = (const float*)d_in[1];       // [B, T] fp32
    const int* bflag = (const int*)d_in[2];       // [B, T] int32
    // d_in[3] = original_len (scalar) — statically T, unused.
    float* out = (float*)d_out;                   // [B, T, D] fp32

    dechunk_fused_kernel<<<BATCH * (TLEN / ROWS_PER_BLOCK), 256, 0, stream>>>(
        z, p, bflag, out);
}